// Round 1
// baseline (5542.720 us; speedup 1.0000x reference)
//
#include <hip/hip_runtime.h>
#include <hip/hip_bf16.h>

#define E_BE      16            // edges per block
#define NG        50            // gaussians
#define HID       512           // hidden dim
#define EMBD      256           // embed dim
#define XDIM      768           // HID + EMBD
#define XSTRIDE   776           // 768 + 8 pad (keeps 16B alignment, breaks pow2 stride)
#define GSTRIDE   52            // 50 + 2 pad

__global__ __launch_bounds__(256) void pair_embed_kernel(
    const int* __restrict__ anum,
    const int* __restrict__ row_index,
    const int* __restrict__ col_index,
    const float* __restrict__ dist,
    const float* __restrict__ W_rbf,
    const float* __restrict__ b_rbf,
    const float* __restrict__ emb_table,
    const float* __restrict__ W1,
    const float* __restrict__ b1,
    const float* __restrict__ W2,
    const float* __restrict__ b2,
    float* __restrict__ out,
    int n_edges)
{
    __shared__ float s_x[E_BE * XSTRIDE];   // [rbf(512) | emb(256)] -> later h(512)
    __shared__ float s_g[E_BE * GSTRIDE];   // gaussians
    __shared__ float s_d[E_BE];
    __shared__ int   s_pid[E_BE];

    const int t  = threadIdx.x;
    const int e0 = blockIdx.x * E_BE;

    // ---- phase 0: per-edge metadata ----
    if (t < E_BE) {
        int e = e0 + t;
        if (e >= n_edges) e = n_edges - 1;   // clamp (500000 % 16 == 0, but be safe)
        s_d[t] = dist[e];
        int r = row_index[e];
        int c = col_index[e];
        s_pid[t] = anum[r] + 100 * anum[c];
    }
    __syncthreads();

    // ---- phase 1a: embedding gather into s_x[e][512..767] ----
    {
        const int lane = t & 63;
        const int rg   = t >> 6;
        for (int e = rg; e < E_BE; e += 4) {
            const float4 v = *reinterpret_cast<const float4*>(
                &emb_table[(size_t)s_pid[e] * EMBD + 4 * lane]);
            *reinterpret_cast<float4*>(&s_x[e * XSTRIDE + HID + 4 * lane]) = v;
        }
    }
    // ---- phase 1b: gaussians ----
    {
        const float spacing = 12.0f / 49.0f;
        const float coeff   = -0.5f / (spacing * spacing);
        for (int idx = t; idx < E_BE * NG; idx += 256) {
            int e = idx / NG;
            int j = idx - e * NG;
            float v = s_d[e] - (float)j * spacing;
            s_g[e * GSTRIDE + j] = expf(coeff * v * v);
        }
    }
    __syncthreads();

    const int c0 = 2 * t;   // this thread's two output columns (0..511)

    // ---- phase 2: rbf[e][c0..c0+1] = g @ W_rbf + b_rbf ----
    {
        float r0[E_BE], r1[E_BE];
        const float bb0 = b_rbf[c0];
        const float bb1 = b_rbf[c0 + 1];
        #pragma unroll
        for (int e = 0; e < E_BE; ++e) { r0[e] = bb0; r1[e] = bb1; }
        for (int j = 0; j < NG; j += 2) {
            const float2 wA = *reinterpret_cast<const float2*>(&W_rbf[(j + 0) * HID + c0]);
            const float2 wB = *reinterpret_cast<const float2*>(&W_rbf[(j + 1) * HID + c0]);
            #pragma unroll
            for (int e = 0; e < E_BE; ++e) {
                const float2 g2 = *reinterpret_cast<const float2*>(&s_g[e * GSTRIDE + j]);
                r0[e] += g2.x * wA.x; r0[e] += g2.y * wB.x;
                r1[e] += g2.x * wA.y; r1[e] += g2.y * wB.y;
            }
        }
        #pragma unroll
        for (int e = 0; e < E_BE; ++e) {
            *reinterpret_cast<float2*>(&s_x[e * XSTRIDE + c0]) = make_float2(r0[e], r1[e]);
        }
    }
    __syncthreads();

    // ---- phase 3: h = silu(x @ W1 + b1) * rbf ----
    float acc0[E_BE], acc1[E_BE];
    {
        const float bb0 = b1[c0];
        const float bb1 = b1[c0 + 1];
        #pragma unroll
        for (int e = 0; e < E_BE; ++e) { acc0[e] = bb0; acc1[e] = bb1; }
        for (int k = 0; k < XDIM; k += 4) {
            const float2 w0 = *reinterpret_cast<const float2*>(&W1[(k + 0) * HID + c0]);
            const float2 w1 = *reinterpret_cast<const float2*>(&W1[(k + 1) * HID + c0]);
            const float2 w2 = *reinterpret_cast<const float2*>(&W1[(k + 2) * HID + c0]);
            const float2 w3 = *reinterpret_cast<const float2*>(&W1[(k + 3) * HID + c0]);
            #pragma unroll
            for (int e = 0; e < E_BE; ++e) {
                const float4 xv = *reinterpret_cast<const float4*>(&s_x[e * XSTRIDE + k]);
                acc0[e] += xv.x * w0.x; acc1[e] += xv.x * w0.y;
                acc0[e] += xv.y * w1.x; acc1[e] += xv.y * w1.y;
                acc0[e] += xv.z * w2.x; acc1[e] += xv.z * w2.y;
                acc0[e] += xv.w * w3.x; acc1[e] += xv.w * w3.y;
            }
        }
        // silu + gate by rbf (rbf still lives in s_x[e][c0..c0+1])
        #pragma unroll
        for (int e = 0; e < E_BE; ++e) {
            const float rb0 = s_x[e * XSTRIDE + c0];
            const float rb1 = s_x[e * XSTRIDE + c0 + 1];
            const float v0 = acc0[e];
            const float v1 = acc1[e];
            acc0[e] = (v0 / (1.0f + expf(-v0))) * rb0;
            acc1[e] = (v1 / (1.0f + expf(-v1))) * rb1;
        }
    }
    __syncthreads();   // all threads done reading x
    #pragma unroll
    for (int e = 0; e < E_BE; ++e) {
        *reinterpret_cast<float2*>(&s_x[e * XSTRIDE + c0]) = make_float2(acc0[e], acc1[e]);
    }
    __syncthreads();

    // ---- phase 4: out[o*E + e] = h[e] @ W2[:,o] + b2[o] ----
    if (t < E_BE * 8) {
        const int o = t >> 4;     // head 0..7
        const int e = t & 15;     // edge in tile
        float a0 = 0.f, a1 = 0.f, a2 = 0.f, a3 = 0.f;
        for (int c = 0; c < HID; c += 4) {
            const float4 hv = *reinterpret_cast<const float4*>(&s_x[e * XSTRIDE + c]);
            a0 += hv.x * W2[(c + 0) * 8 + o];
            a1 += hv.y * W2[(c + 1) * 8 + o];
            a2 += hv.z * W2[(c + 2) * 8 + o];
            a3 += hv.w * W2[(c + 3) * 8 + o];
        }
        const int eg = e0 + e;
        if (eg < n_edges) {
            out[(size_t)o * n_edges + eg] = (a0 + a1) + (a2 + a3) + b2[o];
        }
    }
}

extern "C" void kernel_launch(void* const* d_in, const int* in_sizes, int n_in,
                              void* d_out, int out_size, void* d_ws, size_t ws_size,
                              hipStream_t stream) {
    const int*   anum      = (const int*)d_in[0];
    const int*   row_index = (const int*)d_in[1];
    const int*   col_index = (const int*)d_in[2];
    const float* dist      = (const float*)d_in[3];
    const float* W_rbf     = (const float*)d_in[4];
    const float* b_rbf     = (const float*)d_in[5];
    const float* emb_table = (const float*)d_in[6];
    const float* W1        = (const float*)d_in[7];
    const float* b1        = (const float*)d_in[8];
    const float* W2        = (const float*)d_in[9];
    const float* b2        = (const float*)d_in[10];
    float* out = (float*)d_out;

    const int n_edges = in_sizes[3];
    const int grid = (n_edges + E_BE - 1) / E_BE;
    pair_embed_kernel<<<grid, 256, 0, stream>>>(
        anum, row_index, col_index, dist, W_rbf, b_rbf, emb_table,
        W1, b1, W2, b2, out, n_edges);
}

// Round 2
// 738.360 us; speedup vs baseline: 7.5068x; 7.5068x over previous
//
#include <hip/hip_runtime.h>
#include <hip/hip_bf16.h>

#define NGAUSS   50
#define HID      512
#define EMBD     256
#define XD       768          // HID + EMBD
#define EBLK     64           // edges per block
#define XPAD     776          // x row stride in elements (1552B: 16B-aligned, 4-bank row shift)
#define GPAD     80           // g row stride (160B: 16B-aligned, 8-bank row shift)
#define NT_TOT   32           // 512/16 n-tiles
#define KT_MAIN  24           // 768/32 k-slices

typedef __attribute__((ext_vector_type(8))) short   bfrag;   // 8 bf16 (A/B operand)
typedef __attribute__((ext_vector_type(4))) float   facc;    // 4 f32 (C/D)
typedef __attribute__((ext_vector_type(8))) unsigned short u16x8;
typedef __attribute__((ext_vector_type(4))) unsigned short u16x4;

static __device__ __forceinline__ unsigned short f2bf(float f) {
    union { float f; unsigned u; } v; v.f = f;
    unsigned r = v.u + 0x7FFF + ((v.u >> 16) & 1);   // RTNE
    return (unsigned short)(r >> 16);
}

// ---------------- K0: one-time weight conversion into fragment-linear bf16 ----------------
// B-fragment for (kt,nt): element j of lane l = W[k = kt*32 + (l>>4)*8 + j][col = nt*16 + (l&15)]
__global__ __launch_bounds__(256) void prep_weights(
    const float* __restrict__ W1, const float* __restrict__ W_rbf, const float* __restrict__ W2,
    unsigned short* __restrict__ W1f, unsigned short* __restrict__ Wrbff, unsigned short* __restrict__ W2f)
{
    const int gid = blockIdx.x * 256 + threadIdx.x;
    const int N1 = KT_MAIN * NT_TOT * 64;            // 49152
    const int N2 = 2 * NT_TOT * 64;                  // 4096
    const int N3 = 16 * 64;                          // 1024
    if (gid < N1) {
        int lane = gid & 63, tmp = gid >> 6, nt = tmp & 31, kt = tmp >> 5;
        int c = nt * 16 + (lane & 15);
        int kb = kt * 32 + ((lane >> 4) << 3);
        #pragma unroll
        for (int j = 0; j < 8; ++j)
            W1f[gid * 8 + j] = f2bf(W1[(size_t)(kb + j) * HID + c]);
    } else if (gid < N1 + N2) {
        int g2 = gid - N1;
        int lane = g2 & 63, tmp = g2 >> 6, nt = tmp & 31, kt = tmp >> 5;
        int c = nt * 16 + (lane & 15);
        int kb = kt * 32 + ((lane >> 4) << 3);
        #pragma unroll
        for (int j = 0; j < 8; ++j) {
            int k = kb + j;
            Wrbff[g2 * 8 + j] = (k < NGAUSS) ? f2bf(W_rbf[(size_t)k * HID + c]) : (unsigned short)0;
        }
    } else if (gid < N1 + N2 + N3) {
        int g3 = gid - N1 - N2;
        int lane = g3 & 63, kt = g3 >> 6;
        int col = lane & 15;
        int kb = kt * 32 + ((lane >> 4) << 3);
        #pragma unroll
        for (int j = 0; j < 8; ++j)
            W2f[g3 * 8 + j] = (col < 8) ? f2bf(W2[(size_t)(kb + j) * 8 + col]) : (unsigned short)0;
    }
}

// ---------------- main fused kernel ----------------
__global__ __launch_bounds__(512, 2) void pair_embed_mfma(
    const int* __restrict__ anum,
    const int* __restrict__ row_index,
    const int* __restrict__ col_index,
    const float* __restrict__ dist,
    const float* __restrict__ b_rbf,
    const float* __restrict__ emb_table,
    const float* __restrict__ b1,
    const float* __restrict__ b2,
    const unsigned short* __restrict__ W1f,
    const unsigned short* __restrict__ Wrbff,
    const unsigned short* __restrict__ W2f,
    float* __restrict__ out,
    int n)
{
    extern __shared__ char smem[];
    unsigned short* s_x = (unsigned short*)smem;                       // [64][XPAD] bf16
    unsigned short* s_g = (unsigned short*)(smem + EBLK * XPAD * 2);   // [64][GPAD] bf16
    float*          s_scr = (float*)(smem + EBLK * XPAD * 2);          // alias over s_g (phase 4)
    float*          s_d  = (float*)(smem + EBLK * XPAD * 2 + EBLK * GPAD * 2);
    int*            s_pid = (int*)(smem + EBLK * XPAD * 2 + EBLK * GPAD * 2 + 256);

    const int t = threadIdx.x, lane = t & 63, w = t >> 6;
    const int e0 = blockIdx.x * EBLK;
    const int lq = lane >> 4;          // quarter 0..3
    const int lr = lane & 15;

    // ---- phase 0: metadata ----
    if (t < EBLK) {
        int e = e0 + t; if (e >= n) e = n - 1;
        s_d[t] = dist[e];
        s_pid[t] = anum[row_index[e]] + 100 * anum[col_index[e]];
    }
    __syncthreads();

    // ---- phase 1a: gaussians -> s_g (bf16) ----
    {
        const float sp = 12.0f / 49.0f;
        const float coeff = -0.5f / (sp * sp);
        int e = t >> 3, j0 = (t & 7) * 8;
        float d = s_d[e];
        u16x8 gv;
        #pragma unroll
        for (int j = 0; j < 8; ++j) {
            int jj = j0 + j;
            float v = d - (float)jj * sp;
            float gq = (jj < NGAUSS) ? __expf(coeff * v * v) : 0.0f;
            gv[j] = f2bf(gq);
        }
        *(u16x8*)&s_g[e * GPAD + j0] = gv;
    }
    // ---- phase 1b: emb gather -> s_x[e][512..767] (bf16) ----
    {
        #pragma unroll
        for (int i = 0; i < 8; ++i) {
            int e = w * 8 + i;
            const float4 v = *(const float4*)&emb_table[(size_t)s_pid[e] * EMBD + lane * 4];
            u16x4 bv; bv[0] = f2bf(v.x); bv[1] = f2bf(v.y); bv[2] = f2bf(v.z); bv[3] = f2bf(v.w);
            *(u16x4*)&s_x[e * XPAD + HID + lane * 4] = bv;
        }
    }
    __syncthreads();

    const int ntb = w * 4;   // this wave's first n-tile (64 cols per wave)

    // ---- phase 2: rbf = g @ W_rbf + b_rbf  (MFMA, K=64 padded) ----
    facc racc[4][4] = {};     // [mt][ntl]
    #pragma unroll
    for (int kt = 0; kt < 2; ++kt) {
        bfrag a[4];
        #pragma unroll
        for (int mt = 0; mt < 4; ++mt)
            a[mt] = *(const bfrag*)&s_g[(mt * 16 + lr) * GPAD + kt * 32 + lq * 8];
        #pragma unroll
        for (int ntl = 0; ntl < 4; ++ntl) {
            bfrag b = *(const bfrag*)&Wrbff[((size_t)(kt * NT_TOT + ntb + ntl) * 64 + lane) * 8];
            #pragma unroll
            for (int mt = 0; mt < 4; ++mt)
                racc[mt][ntl] = __builtin_amdgcn_mfma_f32_16x16x32_bf16(a[mt], b, racc[mt][ntl], 0, 0, 0);
        }
    }
    // bias; keep fp32 in regs for the gate; store bf16 copy into s_x[:, 0..511]
    float rbf_reg[4][4][4];
    #pragma unroll
    for (int ntl = 0; ntl < 4; ++ntl) {
        int col = (ntb + ntl) * 16 + lr;
        float bb = b_rbf[col];
        #pragma unroll
        for (int mt = 0; mt < 4; ++mt) {
            #pragma unroll
            for (int r = 0; r < 4; ++r) {
                float vv = racc[mt][ntl][r] + bb;
                rbf_reg[mt][ntl][r] = vv;
                s_x[(mt * 16 + lq * 4 + r) * XPAD + col] = f2bf(vv);
            }
        }
    }
    __syncthreads();

    // ---- phase 3: main GEMM  preact = x @ W1 ----
    facc acc[4][4] = {};
    {
        const unsigned short* pB = W1f + ((size_t)ntb * 64 + lane) * 8;
        #pragma unroll 4
        for (int kt = 0; kt < KT_MAIN; ++kt) {
            bfrag a[4];
            #pragma unroll
            for (int mt = 0; mt < 4; ++mt)
                a[mt] = *(const bfrag*)&s_x[(mt * 16 + lr) * XPAD + kt * 32 + lq * 8];
            #pragma unroll
            for (int ntl = 0; ntl < 4; ++ntl) {
                bfrag b = *(const bfrag*)&pB[(size_t)kt * NT_TOT * 64 * 8 + ntl * 64 * 8];
                #pragma unroll
                for (int mt = 0; mt < 4; ++mt)
                    acc[mt][ntl] = __builtin_amdgcn_mfma_f32_16x16x32_bf16(a[mt], b, acc[mt][ntl], 0, 0, 0);
            }
        }
    }
    __syncthreads();   // everyone done reading x

    // ---- epilogue: h = silu(preact + b1) * rbf ; write h (bf16) over s_x[:, 0..511] ----
    #pragma unroll
    for (int ntl = 0; ntl < 4; ++ntl) {
        int col = (ntb + ntl) * 16 + lr;
        float bb = b1[col];
        #pragma unroll
        for (int mt = 0; mt < 4; ++mt) {
            #pragma unroll
            for (int r = 0; r < 4; ++r) {
                float v = acc[mt][ntl][r] + bb;
                float sg = __builtin_amdgcn_rcpf(1.0f + __expf(-v));
                float h = v * sg * rbf_reg[mt][ntl][r];
                s_x[(mt * 16 + lq * 4 + r) * XPAD + col] = f2bf(h);
            }
        }
    }
    __syncthreads();

    // ---- phase 4: att = h @ W2 (+b2), N padded to 16; waves pair-split K ----
    {
        const int mt = w & 3, kh = w >> 2;
        facc a4 = {};
        #pragma unroll
        for (int kq = 0; kq < 8; ++kq) {
            int kt = kh * 8 + kq;
            bfrag av = *(const bfrag*)&s_x[(mt * 16 + lr) * XPAD + kt * 32 + lq * 8];
            bfrag bv = *(const bfrag*)&W2f[((size_t)kt * 64 + lane) * 8];
            a4 = __builtin_amdgcn_mfma_f32_16x16x32_bf16(av, bv, a4, 0, 0, 0);
        }
        if (w >= 4) *(facc*)&s_scr[((w - 4) * 64 + lane) * 4] = a4;
        __syncthreads();
        if (w < 4) {
            facc oth = *(const facc*)&s_scr[((size_t)w * 64 + lane) * 4];
            int col = lr;
            if (col < 8) {
                float bb = b2[col];
                #pragma unroll
                for (int r = 0; r < 4; ++r) {
                    int e = e0 + mt * 16 + lq * 4 + r;
                    if (e < n) out[(size_t)col * n + e] = a4[r] + oth[r] + bb;
                }
            }
        }
    }
}

extern "C" void kernel_launch(void* const* d_in, const int* in_sizes, int n_in,
                              void* d_out, int out_size, void* d_ws, size_t ws_size,
                              hipStream_t stream) {
    const int*   anum      = (const int*)d_in[0];
    const int*   row_index = (const int*)d_in[1];
    const int*   col_index = (const int*)d_in[2];
    const float* dist      = (const float*)d_in[3];
    const float* W_rbf     = (const float*)d_in[4];
    const float* b_rbf     = (const float*)d_in[5];
    const float* emb_table = (const float*)d_in[6];
    const float* W1        = (const float*)d_in[7];
    const float* b1        = (const float*)d_in[8];
    const float* W2        = (const float*)d_in[9];
    const float* b2        = (const float*)d_in[10];
    float* out = (float*)d_out;

    unsigned short* W1f   = (unsigned short*)d_ws;                    // 24*32*64*8 = 393216
    unsigned short* Wrbff = W1f + (size_t)KT_MAIN * NT_TOT * 64 * 8;  // 2*32*64*8  = 32768
    unsigned short* W2f   = Wrbff + (size_t)2 * NT_TOT * 64 * 8;      // 16*64*8    = 8192

    const int n_edges = in_sizes[3];

    prep_weights<<<213, 256, 0, stream>>>(W1, W_rbf, W2, W1f, Wrbff, W2f);

    const int grid = (n_edges + EBLK - 1) / EBLK;
    const size_t lds_bytes = (size_t)EBLK * XPAD * 2 + (size_t)EBLK * GPAD * 2 + 256 + 256;
    pair_embed_mfma<<<grid, 512, lds_bytes, stream>>>(
        anum, row_index, col_index, dist, b_rbf, emb_table, b1, b2,
        W1f, Wrbff, W2f, out, n_edges);
}